// Round 6
// baseline (634.463 us; speedup 1.0000x reference)
//
#include <hip/hip_runtime.h>
#include <hip/hip_bf16.h>
#include <hip/hip_fp16.h>

// NodeGCN: 3x GCNConv(H=20) + BN/ReLU + final linear, N=100K, E=3.2M.
// R5 changes vs R4:
//  - agg: nontemporal se loads (edge stream no longer evicts the 4MB L2-resident
//    hs), row gathered as uint4+uint4+uint2 (3 VMEM instr vs 5), 8 lanes/node
//    (shfl_xor 1,2,4) for latency hiding / load balance.
//  - finalize: LDS stage CAP 8192->5632 (~47KB LDS -> 3 blocks/CU).
// R4 retained: fp16 hs (4MB = per-XCD L2), bucketed counting-sort CSR build,
// BN scale folded into next W + shift pre-agg (cvec), BN folded into final linear.

#define HD 20
#define EPS 1e-5f
#define BSH 7            // 128 nodes per bucket
#define NBMAX 1024
#define CAP 5632         // max edges per bucket held in LDS (mean ~4092, max ~4400)

__global__ __launch_bounds__(1024)
void init_kernel(int* bcnt, float* stats, float* zero20, int nbv) {
    int t = threadIdx.x;
    if (t < nbv) bcnt[t] = 0;
    if (t < 80) stats[t] = 0.0f;
    if (t < HD) zero20[t] = 0.0f;
}

__global__ __launch_bounds__(256)
void bucket_hist_kernel(const int* __restrict__ dst, int* __restrict__ bcnt,
                        int E, int chunk, int nbv) {
    __shared__ int lh[NBMAX];
    for (int i = threadIdx.x; i < nbv; i += 256) lh[i] = 0;
    __syncthreads();
    int s = blockIdx.x * chunk;
    int e = s + chunk; if (e > E) e = E;
    for (int j = s + threadIdx.x; j < e; j += 256)
        atomicAdd(&lh[dst[j] >> BSH], 1);
    __syncthreads();
    for (int i = threadIdx.x; i < nbv; i += 256)
        if (lh[i]) atomicAdd(&bcnt[i], lh[i]);
}

// single block: exclusive scan bcnt[0..nbv) -> bstart, init bcur, row_start[N]=E
__global__ __launch_bounds__(1024)
void bucket_scan_kernel(const int* __restrict__ bcnt, int* __restrict__ bstart,
                        int* __restrict__ bcur, int* __restrict__ row_start,
                        int n, int E, int nbv) {
    __shared__ int s[1024];
    int t = threadIdx.x;
    int v = (t < nbv) ? bcnt[t] : 0;
    s[t] = v;
    __syncthreads();
    for (int off = 1; off < 1024; off <<= 1) {
        int u = (t >= off) ? s[t - off] : 0;
        __syncthreads();
        s[t] += u;
        __syncthreads();
    }
    if (t < nbv) { int st = s[t] - v; bstart[t] = st; bcur[t] = st; }
    if (t == 0) { bstart[nbv] = E; row_start[n] = E; }
}

// scatter edges into bucket-grouped tmp; payload packed (src | local<<20, ew)
__global__ __launch_bounds__(256)
void scatter_kernel(const int* __restrict__ src, const int* __restrict__ dst,
                    const float* __restrict__ ew, int* __restrict__ bcur,
                    int2* __restrict__ tmp, int E, int chunk, int nbv) {
    __shared__ int lh[NBMAX];
    __shared__ int lbase[NBMAX];
    for (int i = threadIdx.x; i < nbv; i += 256) lh[i] = 0;
    __syncthreads();
    int s = blockIdx.x * chunk;
    int e = s + chunk; if (e > E) e = E;
    for (int j = s + threadIdx.x; j < e; j += 256)
        atomicAdd(&lh[dst[j] >> BSH], 1);
    __syncthreads();
    for (int i = threadIdx.x; i < nbv; i += 256) {
        int c = lh[i];
        lbase[i] = c ? atomicAdd(&bcur[i], c) : 0;
        lh[i] = 0;                         // reuse as local cursor
    }
    __syncthreads();
    for (int j = s + threadIdx.x; j < e; j += 256) {
        int d = dst[j];
        int b = d >> BSH;
        int pos = atomicAdd(&lh[b], 1);
        tmp[lbase[b] + pos] = make_int2(src[j] | ((d & ((1 << BSH) - 1)) << 20),
                                        __float_as_int(ew[j]));
    }
}

// one block per bucket: in-LDS counting sort by local dst; emit CSR + row_start + dinv
__global__ __launch_bounds__(256)
void finalize_kernel(const int2* __restrict__ tmp, const int* __restrict__ bstart,
                     int2* __restrict__ se, int* __restrict__ row_start,
                     float* __restrict__ dinv, int n) {
    __shared__ int hist[128];
    __shared__ float degs[128];
    __shared__ int off[128];
    __shared__ int cur[128];
    __shared__ int2 stage[CAP];
    int b = blockIdx.x;
    int s0 = bstart[b], s1 = bstart[b + 1];
    int cnt = s1 - s0;
    int t = threadIdx.x;
    if (t < 128) { hist[t] = 0; degs[t] = 0.0f; cur[t] = 0; }
    __syncthreads();
    for (int j = s0 + t; j < s1; j += 256) {
        int2 r = tmp[j];
        int l = r.x >> 20;
        atomicAdd(&hist[l], 1);
        atomicAdd(&degs[l], __int_as_float(r.y));
    }
    __syncthreads();
    if (t < 128) off[t] = hist[t];
    __syncthreads();
    for (int o = 1; o < 128; o <<= 1) {           // inclusive scan
        int u = (t < 128 && t >= o) ? off[t - o] : 0;
        __syncthreads();
        if (t < 128) off[t] += u;
        __syncthreads();
    }
    if (t < 128) {
        int node = (b << BSH) + t;
        if (node < n) {
            row_start[node] = s0 + off[t] - hist[t];   // exclusive
            dinv[node] = rsqrtf(1.0f + degs[t]);
        }
    }
    __syncthreads();
    if (cnt <= CAP) {
        for (int j = s0 + t; j < s1; j += 256) {
            int2 r = tmp[j];
            int l = r.x >> 20;
            int p = (off[l] - hist[l]) + atomicAdd(&cur[l], 1);
            stage[p] = make_int2(r.x & 0xFFFFF, r.y);
        }
        __syncthreads();
        for (int k = t; k < cnt; k += 256) se[s0 + k] = stage[k];
    } else {   // overflow fallback (correctness net; not taken for this input)
        for (int j = s0 + t; j < s1; j += 256) {
            int2 r = tmp[j];
            int l = r.x >> 20;
            int p = (off[l] - hist[l]) + atomicAdd(&cur[l], 1);
            se[s0 + p] = make_int2(r.x & 0xFFFFF, r.y);
        }
    }
}

// hs[n,20](fp16) = ((in[n,FIN] @ W[FIN,20]) + cvec) * dinv[n]
template<int FIN, int NPB>
__global__ __launch_bounds__(256)
void gemm_kernel(const float* __restrict__ in, const float* __restrict__ W,
                 const float* __restrict__ cvec, const float* __restrict__ dinv,
                 __half* __restrict__ hs, int n) {
    __shared__ float sWt[HD][FIN + 4];
    __shared__ float sIn[NPB][FIN + 4];
    __shared__ float sC[HD];
    for (int i = threadIdx.x; i < FIN * HD; i += 256) {
        int k = i / HD, f = i % HD;           // W row-major [k][f]
        sWt[f][k] = W[i];
    }
    if (threadIdx.x < HD) sC[threadIdx.x] = cvec[threadIdx.x];
    int base = blockIdx.x * NPB;
    int nb = n - base; if (nb > NPB) nb = NPB;
    int lim = n * FIN;
    const int Q = FIN / 4;
    for (int i = threadIdx.x; i < NPB * Q; i += 256) {
        int row = i / Q, c = (i % Q) * 4;
        int g = (base + row) * FIN + c;
        *(float4*)&sIn[row][c] = (g < lim) ? *(const float4*)&in[g]
                                           : make_float4(0.f, 0.f, 0.f, 0.f);
    }
    __syncthreads();
    for (int idx = threadIdx.x; idx < NPB * HD; idx += 256) {
        int nl = idx / HD, f = idx % HD;
        float4 a = make_float4(0.f, 0.f, 0.f, 0.f);
        #pragma unroll 4
        for (int k = 0; k < FIN; k += 4) {
            float4 x4 = *(const float4*)&sIn[nl][k];
            float4 w4 = *(const float4*)&sWt[f][k];
            a.x = fmaf(x4.x, w4.x, a.x);
            a.y = fmaf(x4.y, w4.y, a.y);
            a.z = fmaf(x4.z, w4.z, a.z);
            a.w = fmaf(x4.w, w4.w, a.w);
        }
        if (nl < nb)
            hs[(base + nl) * HD + f] = __float2half_rn(
                (((a.x + a.y) + (a.z + a.w)) + sC[f]) * dinv[base + nl]);
    }
}

#define FMA4(A, V, W) \
    A.x = fmaf(V.x, W, A.x); A.y = fmaf(V.y, W, A.y); \
    A.z = fmaf(V.z, W, A.z); A.w = fmaf(V.w, W, A.w);

// load a 40B fp16 row (8B-aligned) with 3 VMEM instructions and unpack to fp32
__device__ __forceinline__ void load_row40(const char* rp, float4& v0, float4& v1,
                                           float4& v2, float4& v3, float4& v4) {
    uint4 A = *(const uint4*)rp;            // halfs 0..7
    uint4 B = *(const uint4*)(rp + 16);     // halfs 8..15
    uint2 C = *(const uint2*)(rp + 32);     // halfs 16..19
    float2 p0 = __half22float2(*reinterpret_cast<const __half2*>(&A.x));
    float2 p1 = __half22float2(*reinterpret_cast<const __half2*>(&A.y));
    float2 p2 = __half22float2(*reinterpret_cast<const __half2*>(&A.z));
    float2 p3 = __half22float2(*reinterpret_cast<const __half2*>(&A.w));
    float2 p4 = __half22float2(*reinterpret_cast<const __half2*>(&B.x));
    float2 p5 = __half22float2(*reinterpret_cast<const __half2*>(&B.y));
    float2 p6 = __half22float2(*reinterpret_cast<const __half2*>(&B.z));
    float2 p7 = __half22float2(*reinterpret_cast<const __half2*>(&B.w));
    float2 p8 = __half22float2(*reinterpret_cast<const __half2*>(&C.x));
    float2 p9 = __half22float2(*reinterpret_cast<const __half2*>(&C.y));
    v0 = make_float4(p0.x, p0.y, p1.x, p1.y);
    v1 = make_float4(p2.x, p2.y, p3.x, p3.y);
    v2 = make_float4(p4.x, p4.y, p5.x, p5.y);
    v3 = make_float4(p6.x, p6.y, p7.x, p7.y);
    v4 = make_float4(p8.x, p8.y, p9.x, p9.y);
}

// one node per 8-lane group; lanes take every 8th edge; shfl_xor(1,2,4) combine.
// se loaded nontemporally (read-once stream must not evict L2-resident hs).
template<bool DO_STATS>
__global__ __launch_bounds__(256)
void agg_kernel(const __half* __restrict__ hs, const float* __restrict__ dinv,
                const int* __restrict__ row_start, const int2* __restrict__ se,
                const float* __restrict__ bias, float4* __restrict__ out,
                float* __restrict__ stat_sum, float* __restrict__ stat_sq, int n) {
    __shared__ float ls[HD], lq[HD];
    if (DO_STATS) {
        if (threadIdx.x < HD) { ls[threadIdx.x] = 0.0f; lq[threadIdx.x] = 0.0f; }
        __syncthreads();
    }
    int t = blockIdx.x * blockDim.x + threadIdx.x;
    int i = t >> 3, lane = t & 7;
    if (i < n) {
        float di = dinv[i];
        int s0 = row_start[i], s1 = row_start[i + 1];
        float4 a0, a1, a2, a3, a4;
        if (lane == 0) {
            load_row40((const char*)hs + (size_t)i * 40, a0, a1, a2, a3, a4);
        } else {
            a0 = a1 = a2 = a3 = a4 = make_float4(0.f, 0.f, 0.f, 0.f);
        }
        for (int j = s0 + lane; j < s1; j += 8) {
            long long sv = __builtin_nontemporal_load((const long long*)(se + j));
            int esrc = (int)(unsigned)(sv & 0xFFFFFFFFll);
            float w = __int_as_float((int)(sv >> 32));
            float4 v0, v1, v2, v3, v4;
            load_row40((const char*)hs + (size_t)esrc * 40, v0, v1, v2, v3, v4);
            FMA4(a0, v0, w) FMA4(a1, v1, w) FMA4(a2, v2, w)
            FMA4(a3, v3, w) FMA4(a4, v4, w)
        }
        #define REDX(A, M) \
            A.x += __shfl_xor(A.x, M); A.y += __shfl_xor(A.y, M); \
            A.z += __shfl_xor(A.z, M); A.w += __shfl_xor(A.w, M);
        #define RED8(A) REDX(A, 1) REDX(A, 2) REDX(A, 4)
        RED8(a0) RED8(a1) RED8(a2) RED8(a3) RED8(a4)
        if (lane == 0) {
            float4 acc[5] = {a0, a1, a2, a3, a4};
            #pragma unroll
            for (int q = 0; q < 5; ++q) {
                float4 bb = *(const float4*)(bias + 4 * q);
                float4 v;
                v.x = fmaxf(fmaf(acc[q].x, di, bb.x), 0.0f);
                v.y = fmaxf(fmaf(acc[q].y, di, bb.y), 0.0f);
                v.z = fmaxf(fmaf(acc[q].z, di, bb.z), 0.0f);
                v.w = fmaxf(fmaf(acc[q].w, di, bb.w), 0.0f);
                out[i * 5 + q] = v;
                if (DO_STATS) {
                    int f = 4 * q;
                    atomicAdd(&ls[f + 0], v.x); atomicAdd(&lq[f + 0], v.x * v.x);
                    atomicAdd(&ls[f + 1], v.y); atomicAdd(&lq[f + 1], v.y * v.y);
                    atomicAdd(&ls[f + 2], v.z); atomicAdd(&lq[f + 2], v.z * v.z);
                    atomicAdd(&ls[f + 3], v.w); atomicAdd(&lq[f + 3], v.w * v.w);
                }
            }
        }
    }
    if (DO_STATS) {
        __syncthreads();
        if (threadIdx.x < HD) {
            atomicAdd(&stat_sum[threadIdx.x], ls[threadIdx.x]);
            atomicAdd(&stat_sq[threadIdx.x], lq[threadIdx.x]);
        }
    }
}

__global__ __launch_bounds__(64)
void bn_finalize_kernel(const float* __restrict__ sum, const float* __restrict__ sq,
                        const float* __restrict__ g, const float* __restrict__ be,
                        float* __restrict__ scale, float* __restrict__ shift, int n) {
    int t = threadIdx.x;
    if (t < HD) {
        float inv_n = 1.0f / (float)n;
        float m = sum[t] * inv_n;
        float var = sq[t] * inv_n - m * m;
        float sc = g[t] * rsqrtf(var + EPS);
        scale[t] = sc;
        shift[t] = be[t] - m * sc;
    }
}

// Wp[k][f] = sc[k]*W[k][f];  cvec[f] = sum_k sh[k]*W[k][f]   (20x20)
__global__ __launch_bounds__(512)
void adjust_w_kernel(const float* __restrict__ W, const float* __restrict__ sc,
                     const float* __restrict__ sh, float* __restrict__ Wp,
                     float* __restrict__ cvec) {
    int t = threadIdx.x;
    if (t < HD * HD) Wp[t] = sc[t / HD] * W[t];
    if (t < HD) {
        float acc = 0.0f;
        #pragma unroll
        for (int k = 0; k < HD; ++k) acc = fmaf(sh[k], W[k * HD + t], acc);
        cvec[t] = acc;
    }
}

// Wlp rows 0..19 *= sc1, 20..39 *= sc2; blp = bl + sh1@Wl[0:20] + sh2@Wl[20:40]
__global__ __launch_bounds__(640)
void adjust_final_kernel(const float* __restrict__ Wl, const float* __restrict__ bl,
                         const float* __restrict__ scsh,
                         float* __restrict__ Wlp, float* __restrict__ blp) {
    int t = threadIdx.x;
    if (t < 600) {
        int k = t / 10;
        float s = (k < 20) ? scsh[k] : (k < 40) ? scsh[40 + (k - 20)] : 1.0f;
        Wlp[t] = s * Wl[t];
    }
    if (t < 10) {
        float acc = bl[t];
        #pragma unroll
        for (int k = 0; k < HD; ++k) acc = fmaf(scsh[20 + k], Wl[k * 10 + t], acc);
        #pragma unroll
        for (int k = 0; k < HD; ++k) acc = fmaf(scsh[60 + k], Wl[(HD + k) * 10 + t], acc);
        blp[t] = acc;
    }
}

__global__ __launch_bounds__(256)
void final_kernel(const float* __restrict__ o1, const float* __restrict__ o2,
                  const float* __restrict__ o3, const float* __restrict__ Wl,
                  const float* __restrict__ bl, float* __restrict__ out, int n) {
    __shared__ float sW[600];
    __shared__ float sb[10];
    for (int i = threadIdx.x; i < 600; i += blockDim.x) sW[i] = Wl[i];
    if (threadIdx.x < 10) sb[threadIdx.x] = bl[threadIdx.x];
    __syncthreads();
    int t = blockIdx.x * blockDim.x + threadIdx.x;
    if (t >= n * 10) return;
    int i = t / 10, c = t % 10;
    float acc = sb[c];
    const float* r1 = o1 + i * HD;
    const float* r2 = o2 + i * HD;
    const float* r3 = o3 + i * HD;
    #pragma unroll
    for (int k = 0; k < HD; ++k) acc = fmaf(r1[k], sW[k * 10 + c], acc);
    #pragma unroll
    for (int k = 0; k < HD; ++k) acc = fmaf(r2[k], sW[(HD + k) * 10 + c], acc);
    #pragma unroll
    for (int k = 0; k < HD; ++k) acc = fmaf(r3[k], sW[(2 * HD + k) * 10 + c], acc);
    out[t] = acc;
}

extern "C" void kernel_launch(void* const* d_in, const int* in_sizes, int n_in,
                              void* d_out, int out_size, void* d_ws, size_t ws_size,
                              hipStream_t stream) {
    const float* x   = (const float*)d_in[0];
    const int*   ei  = (const int*)d_in[1];
    const float* ew  = (const float*)d_in[2];
    const float* W1  = (const float*)d_in[3];
    const float* b1  = (const float*)d_in[4];
    const float* g1  = (const float*)d_in[5];
    const float* be1 = (const float*)d_in[6];
    const float* W2  = (const float*)d_in[7];
    const float* b2  = (const float*)d_in[8];
    const float* g2  = (const float*)d_in[9];
    const float* be2 = (const float*)d_in[10];
    const float* W3  = (const float*)d_in[11];
    const float* b3  = (const float*)d_in[12];
    const float* Wl  = (const float*)d_in[13];
    const float* bl  = (const float*)d_in[14];
    float* out = (float*)d_out;

    const int F = in_sizes[3] / HD;       // 128
    const int N = in_sizes[0] / F;        // 100000
    const int E = in_sizes[2];            // 3200000
    const int* src = ei;
    const int* dst = ei + E;
    const int nbv = (N + 127) >> BSH;     // 782 buckets

    char* p = (char*)d_ws;
    auto alloc = [&](size_t bytes) -> void* {
        void* r = (void*)p;
        p += (bytes + 255) & ~(size_t)255;
        return r;
    };
    size_t nh4 = (size_t)N * HD * 4;                         // 8e6 B
    int2*  se      = (int2*) alloc((size_t)E * 8);           // CSR payload (src, ew)
    char*  regionA = (char*) alloc((size_t)E * 8);           // tmp -> hs|o3|o1r
    float* o2r     = (float*)alloc(nh4);
    float* dinv    = (float*)alloc((size_t)N * 4);
    int*   row_start = (int*)alloc((size_t)(N + 1) * 4);
    int*   bcnt    = (int*)  alloc(NBMAX * 4);
    int*   bstart  = (int*)  alloc((NBMAX + 1) * 4);
    int*   bcur    = (int*)  alloc(NBMAX * 4);
    float* stats   = (float*)alloc(80 * 4);   // sum1,sq1,sum2,sq2
    float* scsh    = (float*)alloc(80 * 4);   // sc1,sh1,sc2,sh2
    float* zero20  = (float*)alloc(20 * 4);
    float* W2p     = (float*)alloc(400 * 4);
    float* c2      = (float*)alloc(20 * 4);
    float* W3p     = (float*)alloc(400 * 4);
    float* c3      = (float*)alloc(20 * 4);
    float* Wlp     = (float*)alloc(600 * 4);
    float* blp     = (float*)alloc(12 * 4);

    int2*   tmp = (int2*)regionA;
    __half* hs  = (__half*)regionA;                 // 4 MB fp16, fits per-XCD L2
    float*  o3  = (float*)(regionA + nh4);
    float*  o1r = (float*)(regionA + 2 * nh4);

    const int B = 256;
    const int GB = 512;                          // blocks for hist/scatter
    const int chunk = (E + GB - 1) / GB;         // 6250
    int gAgg = (8 * N + B - 1) / B;              // 3125 (8 lanes/node)
    int gNC  = (N * 10 + B - 1) / B;

    // ---- graph build (shared by all 3 layers) ----
    hipLaunchKernelGGL(init_kernel, dim3(1), dim3(1024), 0, stream, bcnt, stats, zero20, nbv);
    hipLaunchKernelGGL(bucket_hist_kernel, dim3(GB), dim3(B), 0, stream, dst, bcnt, E, chunk, nbv);
    hipLaunchKernelGGL(bucket_scan_kernel, dim3(1), dim3(1024), 0, stream,
                       bcnt, bstart, bcur, row_start, N, E, nbv);
    hipLaunchKernelGGL(scatter_kernel, dim3(GB), dim3(B), 0, stream,
                       src, dst, ew, bcur, tmp, E, chunk, nbv);
    hipLaunchKernelGGL(finalize_kernel, dim3(nbv), dim3(B), 0, stream,
                       tmp, bstart, se, row_start, dinv, N);

    // ---- layer 1 (no upstream BN: cvec = 0, bias = b1) ----
    hipLaunchKernelGGL((gemm_kernel<128, 16>), dim3((N + 15) / 16), dim3(B), 0, stream,
                       x, W1, zero20, dinv, hs, N);
    hipLaunchKernelGGL((agg_kernel<true>), dim3(gAgg), dim3(B), 0, stream,
                       hs, dinv, row_start, se, b1, (float4*)o1r,
                       stats, stats + 20, N);
    hipLaunchKernelGGL(bn_finalize_kernel, dim3(1), dim3(64), 0, stream,
                       stats, stats + 20, g1, be1, scsh, scsh + 20, N);
    hipLaunchKernelGGL(adjust_w_kernel, dim3(1), dim3(512), 0, stream,
                       W2, scsh, scsh + 20, W2p, c2);

    // ---- layer 2 (BN1 scale in W2p, shift in c2 pre-agg; bias = raw b2) ----
    hipLaunchKernelGGL((gemm_kernel<HD, 64>), dim3((N + 63) / 64), dim3(B), 0, stream,
                       o1r, W2p, c2, dinv, hs, N);
    hipLaunchKernelGGL((agg_kernel<true>), dim3(gAgg), dim3(B), 0, stream,
                       hs, dinv, row_start, se, b2, (float4*)o2r,
                       stats + 40, stats + 60, N);
    hipLaunchKernelGGL(bn_finalize_kernel, dim3(1), dim3(64), 0, stream,
                       stats + 40, stats + 60, g2, be2, scsh + 40, scsh + 60, N);
    hipLaunchKernelGGL(adjust_w_kernel, dim3(1), dim3(512), 0, stream,
                       W3, scsh + 40, scsh + 60, W3p, c3);

    // ---- layer 3 (BN2 scale in W3p, shift in c3 pre-agg; bias = raw b3) ----
    hipLaunchKernelGGL((gemm_kernel<HD, 64>), dim3((N + 63) / 64), dim3(B), 0, stream,
                       o2r, W3p, c3, dinv, hs, N);
    hipLaunchKernelGGL((agg_kernel<false>), dim3(gAgg), dim3(B), 0, stream,
                       hs, dinv, row_start, se, b3, (float4*)o3,
                       nullptr, nullptr, N);

    // ---- final linear on raw o1r/o2r with BN folded into Wlp/blp (exact) ----
    hipLaunchKernelGGL(adjust_final_kernel, dim3(1), dim3(640), 0, stream,
                       Wl, bl, scsh, Wlp, blp);
    hipLaunchKernelGGL(final_kernel, dim3(gNC), dim3(B), 0, stream,
                       o1r, o2r, o3, Wlp, blp, out, N);
}

// Round 7
// 603.846 us; speedup vs baseline: 1.0507x; 1.0507x over previous
//
#include <hip/hip_runtime.h>
#include <hip/hip_bf16.h>
#include <hip/hip_fp16.h>

// NodeGCN: 3x GCNConv(H=20) + BN/ReLU + final linear, N=100K, E=3.2M.
// R6 changes vs R5 (which regressed: misaligned uint4 row loads + 8-lane
// over-split):
//  - revert agg to R4's 4 lanes/node + regular se loads (proven fastest),
//  - hs split into hsA (halfs 0..15, 32B/node) + hsB (halfs 16..19, 8B/node):
//    per-edge gather = 2x aligned dwordx4 + 1x aligned dwordx2 (3 VMEM, was 5),
//    total table still 4MB = per-XCD L2.
//  - keep finalize CAP 5632 (~47KB LDS -> 3 blocks/CU).

#define HD 20
#define EPS 1e-5f
#define BSH 7            // 128 nodes per bucket
#define NBMAX 1024
#define CAP 5632         // max edges per bucket held in LDS (mean ~4092)

__global__ __launch_bounds__(1024)
void init_kernel(int* bcnt, float* stats, float* zero20, int nbv) {
    int t = threadIdx.x;
    if (t < nbv) bcnt[t] = 0;
    if (t < 80) stats[t] = 0.0f;
    if (t < HD) zero20[t] = 0.0f;
}

__global__ __launch_bounds__(256)
void bucket_hist_kernel(const int* __restrict__ dst, int* __restrict__ bcnt,
                        int E, int chunk, int nbv) {
    __shared__ int lh[NBMAX];
    for (int i = threadIdx.x; i < nbv; i += 256) lh[i] = 0;
    __syncthreads();
    int s = blockIdx.x * chunk;
    int e = s + chunk; if (e > E) e = E;
    for (int j = s + threadIdx.x; j < e; j += 256)
        atomicAdd(&lh[dst[j] >> BSH], 1);
    __syncthreads();
    for (int i = threadIdx.x; i < nbv; i += 256)
        if (lh[i]) atomicAdd(&bcnt[i], lh[i]);
}

// single block: exclusive scan bcnt[0..nbv) -> bstart, init bcur, row_start[N]=E
__global__ __launch_bounds__(1024)
void bucket_scan_kernel(const int* __restrict__ bcnt, int* __restrict__ bstart,
                        int* __restrict__ bcur, int* __restrict__ row_start,
                        int n, int E, int nbv) {
    __shared__ int s[1024];
    int t = threadIdx.x;
    int v = (t < nbv) ? bcnt[t] : 0;
    s[t] = v;
    __syncthreads();
    for (int off = 1; off < 1024; off <<= 1) {
        int u = (t >= off) ? s[t - off] : 0;
        __syncthreads();
        s[t] += u;
        __syncthreads();
    }
    if (t < nbv) { int st = s[t] - v; bstart[t] = st; bcur[t] = st; }
    if (t == 0) { bstart[nbv] = E; row_start[n] = E; }
}

// scatter edges into bucket-grouped tmp; payload packed (src | local<<20, ew)
__global__ __launch_bounds__(256)
void scatter_kernel(const int* __restrict__ src, const int* __restrict__ dst,
                    const float* __restrict__ ew, int* __restrict__ bcur,
                    int2* __restrict__ tmp, int E, int chunk, int nbv) {
    __shared__ int lh[NBMAX];
    __shared__ int lbase[NBMAX];
    for (int i = threadIdx.x; i < nbv; i += 256) lh[i] = 0;
    __syncthreads();
    int s = blockIdx.x * chunk;
    int e = s + chunk; if (e > E) e = E;
    for (int j = s + threadIdx.x; j < e; j += 256)
        atomicAdd(&lh[dst[j] >> BSH], 1);
    __syncthreads();
    for (int i = threadIdx.x; i < nbv; i += 256) {
        int c = lh[i];
        lbase[i] = c ? atomicAdd(&bcur[i], c) : 0;
        lh[i] = 0;                         // reuse as local cursor
    }
    __syncthreads();
    for (int j = s + threadIdx.x; j < e; j += 256) {
        int d = dst[j];
        int b = d >> BSH;
        int pos = atomicAdd(&lh[b], 1);
        tmp[lbase[b] + pos] = make_int2(src[j] | ((d & ((1 << BSH) - 1)) << 20),
                                        __float_as_int(ew[j]));
    }
}

// one block per bucket: in-LDS counting sort by local dst; emit CSR + row_start + dinv
__global__ __launch_bounds__(256)
void finalize_kernel(const int2* __restrict__ tmp, const int* __restrict__ bstart,
                     int2* __restrict__ se, int* __restrict__ row_start,
                     float* __restrict__ dinv, int n) {
    __shared__ int hist[128];
    __shared__ float degs[128];
    __shared__ int off[128];
    __shared__ int cur[128];
    __shared__ int2 stage[CAP];
    int b = blockIdx.x;
    int s0 = bstart[b], s1 = bstart[b + 1];
    int cnt = s1 - s0;
    int t = threadIdx.x;
    if (t < 128) { hist[t] = 0; degs[t] = 0.0f; cur[t] = 0; }
    __syncthreads();
    for (int j = s0 + t; j < s1; j += 256) {
        int2 r = tmp[j];
        int l = r.x >> 20;
        atomicAdd(&hist[l], 1);
        atomicAdd(&degs[l], __int_as_float(r.y));
    }
    __syncthreads();
    if (t < 128) off[t] = hist[t];
    __syncthreads();
    for (int o = 1; o < 128; o <<= 1) {           // inclusive scan
        int u = (t < 128 && t >= o) ? off[t - o] : 0;
        __syncthreads();
        if (t < 128) off[t] += u;
        __syncthreads();
    }
    if (t < 128) {
        int node = (b << BSH) + t;
        if (node < n) {
            row_start[node] = s0 + off[t] - hist[t];   // exclusive
            dinv[node] = rsqrtf(1.0f + degs[t]);
        }
    }
    __syncthreads();
    if (cnt <= CAP) {
        for (int j = s0 + t; j < s1; j += 256) {
            int2 r = tmp[j];
            int l = r.x >> 20;
            int p = (off[l] - hist[l]) + atomicAdd(&cur[l], 1);
            stage[p] = make_int2(r.x & 0xFFFFF, r.y);
        }
        __syncthreads();
        for (int k = t; k < cnt; k += 256) se[s0 + k] = stage[k];
    } else {   // overflow fallback (correctness net; not taken for this input)
        for (int j = s0 + t; j < s1; j += 256) {
            int2 r = tmp[j];
            int l = r.x >> 20;
            int p = (off[l] - hist[l]) + atomicAdd(&cur[l], 1);
            se[s0 + p] = make_int2(r.x & 0xFFFFF, r.y);
        }
    }
}

// hsA[n][16 halfs], hsB[n][4 halfs] = ((in[n,FIN] @ W[FIN,20]) + cvec) * dinv[n]
template<int FIN, int NPB>
__global__ __launch_bounds__(256)
void gemm_kernel(const float* __restrict__ in, const float* __restrict__ W,
                 const float* __restrict__ cvec, const float* __restrict__ dinv,
                 __half* __restrict__ hsA, __half* __restrict__ hsB, int n) {
    __shared__ float sWt[HD][FIN + 4];
    __shared__ float sIn[NPB][FIN + 4];
    __shared__ float sC[HD];
    for (int i = threadIdx.x; i < FIN * HD; i += 256) {
        int k = i / HD, f = i % HD;           // W row-major [k][f]
        sWt[f][k] = W[i];
    }
    if (threadIdx.x < HD) sC[threadIdx.x] = cvec[threadIdx.x];
    int base = blockIdx.x * NPB;
    int nb = n - base; if (nb > NPB) nb = NPB;
    int lim = n * FIN;
    const int Q = FIN / 4;
    for (int i = threadIdx.x; i < NPB * Q; i += 256) {
        int row = i / Q, c = (i % Q) * 4;
        int g = (base + row) * FIN + c;
        *(float4*)&sIn[row][c] = (g < lim) ? *(const float4*)&in[g]
                                           : make_float4(0.f, 0.f, 0.f, 0.f);
    }
    __syncthreads();
    for (int idx = threadIdx.x; idx < NPB * HD; idx += 256) {
        int nl = idx / HD, f = idx % HD;
        float4 a = make_float4(0.f, 0.f, 0.f, 0.f);
        #pragma unroll 4
        for (int k = 0; k < FIN; k += 4) {
            float4 x4 = *(const float4*)&sIn[nl][k];
            float4 w4 = *(const float4*)&sWt[f][k];
            a.x = fmaf(x4.x, w4.x, a.x);
            a.y = fmaf(x4.y, w4.y, a.y);
            a.z = fmaf(x4.z, w4.z, a.z);
            a.w = fmaf(x4.w, w4.w, a.w);
        }
        if (nl < nb) {
            int i = base + nl;
            __half hv = __float2half_rn(
                (((a.x + a.y) + (a.z + a.w)) + sC[f]) * dinv[i]);
            if (f < 16) hsA[i * 16 + f] = hv;
            else        hsB[i * 4 + (f - 16)] = hv;
        }
    }
}

#define FMA4(A, V, W) \
    A.x = fmaf(V.x, W, A.x); A.y = fmaf(V.y, W, A.y); \
    A.z = fmaf(V.z, W, A.z); A.w = fmaf(V.w, W, A.w);

__device__ __forceinline__ float4 h4f(uint lo, uint hi) {
    float2 f0 = __half22float2(*reinterpret_cast<const __half2*>(&lo));
    float2 f1 = __half22float2(*reinterpret_cast<const __half2*>(&hi));
    return make_float4(f0.x, f0.y, f1.x, f1.y);
}

// load node row from split tables: 2x aligned dwordx4 + 1x aligned dwordx2
__device__ __forceinline__ void load_row(const uint4* __restrict__ hsA4,
                                         const uint2* __restrict__ hsB2, int i,
                                         float4& v0, float4& v1, float4& v2,
                                         float4& v3, float4& v4) {
    uint4 A = hsA4[2 * i];
    uint4 B = hsA4[2 * i + 1];
    uint2 C = hsB2[i];
    v0 = h4f(A.x, A.y);
    v1 = h4f(A.z, A.w);
    v2 = h4f(B.x, B.y);
    v3 = h4f(B.z, B.w);
    v4 = h4f(C.x, C.y);
}

// one node per 4-lane group; lanes take every 4th edge; shfl_xor(1,2) combine.
template<bool DO_STATS>
__global__ __launch_bounds__(256)
void agg_kernel(const uint4* __restrict__ hsA4, const uint2* __restrict__ hsB2,
                const float* __restrict__ dinv, const int* __restrict__ row_start,
                const int2* __restrict__ se, const float* __restrict__ bias,
                float4* __restrict__ out, float* __restrict__ stat_sum,
                float* __restrict__ stat_sq, int n) {
    __shared__ float ls[HD], lq[HD];
    if (DO_STATS) {
        if (threadIdx.x < HD) { ls[threadIdx.x] = 0.0f; lq[threadIdx.x] = 0.0f; }
        __syncthreads();
    }
    int t = blockIdx.x * blockDim.x + threadIdx.x;
    int i = t >> 2, lane = t & 3;
    if (i < n) {
        float di = dinv[i];
        int s0 = row_start[i], s1 = row_start[i + 1];
        float4 a0, a1, a2, a3, a4;
        if (lane == 0) {
            load_row(hsA4, hsB2, i, a0, a1, a2, a3, a4);   // self-loop term
        } else {
            a0 = a1 = a2 = a3 = a4 = make_float4(0.f, 0.f, 0.f, 0.f);
        }
        for (int j = s0 + lane; j < s1; j += 4) {
            int2 e = se[j];
            float w = __int_as_float(e.y);
            float4 v0, v1, v2, v3, v4;
            load_row(hsA4, hsB2, e.x, v0, v1, v2, v3, v4);
            FMA4(a0, v0, w) FMA4(a1, v1, w) FMA4(a2, v2, w)
            FMA4(a3, v3, w) FMA4(a4, v4, w)
        }
        #define REDX(A, M) \
            A.x += __shfl_xor(A.x, M); A.y += __shfl_xor(A.y, M); \
            A.z += __shfl_xor(A.z, M); A.w += __shfl_xor(A.w, M);
        #define RED4L(A) REDX(A, 1) REDX(A, 2)
        RED4L(a0) RED4L(a1) RED4L(a2) RED4L(a3) RED4L(a4)
        if (lane == 0) {
            float4 acc[5] = {a0, a1, a2, a3, a4};
            #pragma unroll
            for (int q = 0; q < 5; ++q) {
                float4 bb = *(const float4*)(bias + 4 * q);
                float4 v;
                v.x = fmaxf(fmaf(acc[q].x, di, bb.x), 0.0f);
                v.y = fmaxf(fmaf(acc[q].y, di, bb.y), 0.0f);
                v.z = fmaxf(fmaf(acc[q].z, di, bb.z), 0.0f);
                v.w = fmaxf(fmaf(acc[q].w, di, bb.w), 0.0f);
                out[i * 5 + q] = v;
                if (DO_STATS) {
                    int f = 4 * q;
                    atomicAdd(&ls[f + 0], v.x); atomicAdd(&lq[f + 0], v.x * v.x);
                    atomicAdd(&ls[f + 1], v.y); atomicAdd(&lq[f + 1], v.y * v.y);
                    atomicAdd(&ls[f + 2], v.z); atomicAdd(&lq[f + 2], v.z * v.z);
                    atomicAdd(&ls[f + 3], v.w); atomicAdd(&lq[f + 3], v.w * v.w);
                }
            }
        }
    }
    if (DO_STATS) {
        __syncthreads();
        if (threadIdx.x < HD) {
            atomicAdd(&stat_sum[threadIdx.x], ls[threadIdx.x]);
            atomicAdd(&stat_sq[threadIdx.x], lq[threadIdx.x]);
        }
    }
}

__global__ __launch_bounds__(64)
void bn_finalize_kernel(const float* __restrict__ sum, const float* __restrict__ sq,
                        const float* __restrict__ g, const float* __restrict__ be,
                        float* __restrict__ scale, float* __restrict__ shift, int n) {
    int t = threadIdx.x;
    if (t < HD) {
        float inv_n = 1.0f / (float)n;
        float m = sum[t] * inv_n;
        float var = sq[t] * inv_n - m * m;
        float sc = g[t] * rsqrtf(var + EPS);
        scale[t] = sc;
        shift[t] = be[t] - m * sc;
    }
}

// Wp[k][f] = sc[k]*W[k][f];  cvec[f] = sum_k sh[k]*W[k][f]   (20x20)
__global__ __launch_bounds__(512)
void adjust_w_kernel(const float* __restrict__ W, const float* __restrict__ sc,
                     const float* __restrict__ sh, float* __restrict__ Wp,
                     float* __restrict__ cvec) {
    int t = threadIdx.x;
    if (t < HD * HD) Wp[t] = sc[t / HD] * W[t];
    if (t < HD) {
        float acc = 0.0f;
        #pragma unroll
        for (int k = 0; k < HD; ++k) acc = fmaf(sh[k], W[k * HD + t], acc);
        cvec[t] = acc;
    }
}

// Wlp rows 0..19 *= sc1, 20..39 *= sc2; blp = bl + sh1@Wl[0:20] + sh2@Wl[20:40]
__global__ __launch_bounds__(640)
void adjust_final_kernel(const float* __restrict__ Wl, const float* __restrict__ bl,
                         const float* __restrict__ scsh,
                         float* __restrict__ Wlp, float* __restrict__ blp) {
    int t = threadIdx.x;
    if (t < 600) {
        int k = t / 10;
        float s = (k < 20) ? scsh[k] : (k < 40) ? scsh[40 + (k - 20)] : 1.0f;
        Wlp[t] = s * Wl[t];
    }
    if (t < 10) {
        float acc = bl[t];
        #pragma unroll
        for (int k = 0; k < HD; ++k) acc = fmaf(scsh[20 + k], Wl[k * 10 + t], acc);
        #pragma unroll
        for (int k = 0; k < HD; ++k) acc = fmaf(scsh[60 + k], Wl[(HD + k) * 10 + t], acc);
        blp[t] = acc;
    }
}

__global__ __launch_bounds__(256)
void final_kernel(const float* __restrict__ o1, const float* __restrict__ o2,
                  const float* __restrict__ o3, const float* __restrict__ Wl,
                  const float* __restrict__ bl, float* __restrict__ out, int n) {
    __shared__ float sW[600];
    __shared__ float sb[10];
    for (int i = threadIdx.x; i < 600; i += blockDim.x) sW[i] = Wl[i];
    if (threadIdx.x < 10) sb[threadIdx.x] = bl[threadIdx.x];
    __syncthreads();
    int t = blockIdx.x * blockDim.x + threadIdx.x;
    if (t >= n * 10) return;
    int i = t / 10, c = t % 10;
    float acc = sb[c];
    const float* r1 = o1 + i * HD;
    const float* r2 = o2 + i * HD;
    const float* r3 = o3 + i * HD;
    #pragma unroll
    for (int k = 0; k < HD; ++k) acc = fmaf(r1[k], sW[k * 10 + c], acc);
    #pragma unroll
    for (int k = 0; k < HD; ++k) acc = fmaf(r2[k], sW[(HD + k) * 10 + c], acc);
    #pragma unroll
    for (int k = 0; k < HD; ++k) acc = fmaf(r3[k], sW[(2 * HD + k) * 10 + c], acc);
    out[t] = acc;
}

extern "C" void kernel_launch(void* const* d_in, const int* in_sizes, int n_in,
                              void* d_out, int out_size, void* d_ws, size_t ws_size,
                              hipStream_t stream) {
    const float* x   = (const float*)d_in[0];
    const int*   ei  = (const int*)d_in[1];
    const float* ew  = (const float*)d_in[2];
    const float* W1  = (const float*)d_in[3];
    const float* b1  = (const float*)d_in[4];
    const float* g1  = (const float*)d_in[5];
    const float* be1 = (const float*)d_in[6];
    const float* W2  = (const float*)d_in[7];
    const float* b2  = (const float*)d_in[8];
    const float* g2  = (const float*)d_in[9];
    const float* be2 = (const float*)d_in[10];
    const float* W3  = (const float*)d_in[11];
    const float* b3  = (const float*)d_in[12];
    const float* Wl  = (const float*)d_in[13];
    const float* bl  = (const float*)d_in[14];
    float* out = (float*)d_out;

    const int F = in_sizes[3] / HD;       // 128
    const int N = in_sizes[0] / F;        // 100000
    const int E = in_sizes[2];            // 3200000
    const int* src = ei;
    const int* dst = ei + E;
    const int nbv = (N + 127) >> BSH;     // 782 buckets

    char* p = (char*)d_ws;
    auto alloc = [&](size_t bytes) -> void* {
        void* r = (void*)p;
        p += (bytes + 255) & ~(size_t)255;
        return r;
    };
    size_t nh4 = (size_t)N * HD * 4;                         // 8e6 B
    int2*  se      = (int2*) alloc((size_t)E * 8);           // CSR payload (src, ew)
    char*  regionA = (char*) alloc((size_t)E * 8);           // tmp -> hsA|hsB|o3|o1r
    float* o2r     = (float*)alloc(nh4);
    float* dinv    = (float*)alloc((size_t)N * 4);
    int*   row_start = (int*)alloc((size_t)(N + 1) * 4);
    int*   bcnt    = (int*)  alloc(NBMAX * 4);
    int*   bstart  = (int*)  alloc((NBMAX + 1) * 4);
    int*   bcur    = (int*)  alloc(NBMAX * 4);
    float* stats   = (float*)alloc(80 * 4);   // sum1,sq1,sum2,sq2
    float* scsh    = (float*)alloc(80 * 4);   // sc1,sh1,sc2,sh2
    float* zero20  = (float*)alloc(20 * 4);
    float* W2p     = (float*)alloc(400 * 4);
    float* c2      = (float*)alloc(20 * 4);
    float* W3p     = (float*)alloc(400 * 4);
    float* c3      = (float*)alloc(20 * 4);
    float* Wlp     = (float*)alloc(600 * 4);
    float* blp     = (float*)alloc(12 * 4);

    int2*   tmp = (int2*)regionA;
    __half* hsA = (__half*)regionA;                    // 3.2 MB (16 halfs/node)
    __half* hsB = (__half*)(regionA + (size_t)N * 32); // 0.8 MB (4 halfs/node)
    float*  o3  = (float*)(regionA + nh4);
    float*  o1r = (float*)(regionA + 2 * nh4);

    const int B = 256;
    const int GB = 512;                          // blocks for hist/scatter
    const int chunk = (E + GB - 1) / GB;         // 6250
    int gAgg = (4 * N + B - 1) / B;              // 1563 (4 lanes/node)
    int gNC  = (N * 10 + B - 1) / B;

    // ---- graph build (shared by all 3 layers) ----
    hipLaunchKernelGGL(init_kernel, dim3(1), dim3(1024), 0, stream, bcnt, stats, zero20, nbv);
    hipLaunchKernelGGL(bucket_hist_kernel, dim3(GB), dim3(B), 0, stream, dst, bcnt, E, chunk, nbv);
    hipLaunchKernelGGL(bucket_scan_kernel, dim3(1), dim3(1024), 0, stream,
                       bcnt, bstart, bcur, row_start, N, E, nbv);
    hipLaunchKernelGGL(scatter_kernel, dim3(GB), dim3(B), 0, stream,
                       src, dst, ew, bcur, tmp, E, chunk, nbv);
    hipLaunchKernelGGL(finalize_kernel, dim3(nbv), dim3(B), 0, stream,
                       tmp, bstart, se, row_start, dinv, N);

    // ---- layer 1 (no upstream BN: cvec = 0, bias = b1) ----
    hipLaunchKernelGGL((gemm_kernel<128, 16>), dim3((N + 15) / 16), dim3(B), 0, stream,
                       x, W1, zero20, dinv, hsA, hsB, N);
    hipLaunchKernelGGL((agg_kernel<true>), dim3(gAgg), dim3(B), 0, stream,
                       (const uint4*)hsA, (const uint2*)hsB, dinv, row_start, se,
                       b1, (float4*)o1r, stats, stats + 20, N);
    hipLaunchKernelGGL(bn_finalize_kernel, dim3(1), dim3(64), 0, stream,
                       stats, stats + 20, g1, be1, scsh, scsh + 20, N);
    hipLaunchKernelGGL(adjust_w_kernel, dim3(1), dim3(512), 0, stream,
                       W2, scsh, scsh + 20, W2p, c2);

    // ---- layer 2 (BN1 scale in W2p, shift in c2 pre-agg; bias = raw b2) ----
    hipLaunchKernelGGL((gemm_kernel<HD, 64>), dim3((N + 63) / 64), dim3(B), 0, stream,
                       o1r, W2p, c2, dinv, hsA, hsB, N);
    hipLaunchKernelGGL((agg_kernel<true>), dim3(gAgg), dim3(B), 0, stream,
                       (const uint4*)hsA, (const uint2*)hsB, dinv, row_start, se,
                       b2, (float4*)o2r, stats + 40, stats + 60, N);
    hipLaunchKernelGGL(bn_finalize_kernel, dim3(1), dim3(64), 0, stream,
                       stats + 40, stats + 60, g2, be2, scsh + 40, scsh + 60, N);
    hipLaunchKernelGGL(adjust_w_kernel, dim3(1), dim3(512), 0, stream,
                       W3, scsh + 40, scsh + 60, W3p, c3);

    // ---- layer 3 (BN2 scale in W3p, shift in c3 pre-agg; bias = raw b3) ----
    hipLaunchKernelGGL((gemm_kernel<HD, 64>), dim3((N + 63) / 64), dim3(B), 0, stream,
                       o2r, W3p, c3, dinv, hsA, hsB, N);
    hipLaunchKernelGGL((agg_kernel<false>), dim3(gAgg), dim3(B), 0, stream,
                       (const uint4*)hsA, (const uint2*)hsB, dinv, row_start, se,
                       b3, (float4*)o3, nullptr, nullptr, N);

    // ---- final linear on raw o1r/o2r with BN folded into Wlp/blp (exact) ----
    hipLaunchKernelGGL(adjust_final_kernel, dim3(1), dim3(640), 0, stream,
                       Wl, bl, scsh, Wlp, blp);
    hipLaunchKernelGGL(final_kernel, dim3(gNC), dim3(B), 0, stream,
                       o1r, o2r, o3, Wlp, blp, out, N);
}

// Round 9
// 536.378 us; speedup vs baseline: 1.1829x; 1.1258x over previous
//
#include <hip/hip_runtime.h>
#include <hip/hip_bf16.h>
#include <hip/hip_fp16.h>

// NodeGCN: 3x GCNConv(H=20) + BN/ReLU + final linear, N=100K, E=3.2M.
// R8 = R7 with the Wlp out-of-bounds fix:
//  bn_adjust2's Wlp scale for rows 40..59 (o3 block) must be 1.0f; R7 read
//  ssc[20..40) out of bounds (silently scaled the o3 third of Wl by garbage).
// R7 structure retained: packed fp16 hs (4MB = per-XCD L2), 4 lanes/node agg
// with 2-deep software-pipelined edge loop, final linear fused into agg3,
// merged BN-finalize+fold kernels, bucketed counting-sort CSR build.

#define HD 20
#define EPS 1e-5f
#define BSH 7            // 128 nodes per bucket
#define NBMAX 1024
#define CAP 5632         // max edges per bucket held in LDS (mean ~4092)

__global__ __launch_bounds__(1024)
void init_kernel(int* bcnt, float* stats, float* zero20, int nbv) {
    int t = threadIdx.x;
    if (t < nbv) bcnt[t] = 0;
    if (t < 80) stats[t] = 0.0f;
    if (t < HD) zero20[t] = 0.0f;
}

__global__ __launch_bounds__(256)
void bucket_hist_kernel(const int* __restrict__ dst, int* __restrict__ bcnt,
                        int E, int chunk, int nbv) {
    __shared__ int lh[NBMAX];
    for (int i = threadIdx.x; i < nbv; i += 256) lh[i] = 0;
    __syncthreads();
    int s = blockIdx.x * chunk;
    int e = s + chunk; if (e > E) e = E;
    for (int j = s + threadIdx.x; j < e; j += 256)
        atomicAdd(&lh[dst[j] >> BSH], 1);
    __syncthreads();
    for (int i = threadIdx.x; i < nbv; i += 256)
        if (lh[i]) atomicAdd(&bcnt[i], lh[i]);
}

// single block: exclusive scan bcnt[0..nbv) -> bstart, init bcur, row_start[N]=E
__global__ __launch_bounds__(1024)
void bucket_scan_kernel(const int* __restrict__ bcnt, int* __restrict__ bstart,
                        int* __restrict__ bcur, int* __restrict__ row_start,
                        int n, int E, int nbv) {
    __shared__ int s[1024];
    int t = threadIdx.x;
    int v = (t < nbv) ? bcnt[t] : 0;
    s[t] = v;
    __syncthreads();
    for (int off = 1; off < 1024; off <<= 1) {
        int u = (t >= off) ? s[t - off] : 0;
        __syncthreads();
        s[t] += u;
        __syncthreads();
    }
    if (t < nbv) { int st = s[t] - v; bstart[t] = st; bcur[t] = st; }
    if (t == 0) { bstart[nbv] = E; row_start[n] = E; }
}

// scatter edges into bucket-grouped tmp; payload packed (src | local<<20, ew)
__global__ __launch_bounds__(256)
void scatter_kernel(const int* __restrict__ src, const int* __restrict__ dst,
                    const float* __restrict__ ew, int* __restrict__ bcur,
                    int2* __restrict__ tmp, int E, int chunk, int nbv) {
    __shared__ int lh[NBMAX];
    __shared__ int lbase[NBMAX];
    for (int i = threadIdx.x; i < nbv; i += 256) lh[i] = 0;
    __syncthreads();
    int s = blockIdx.x * chunk;
    int e = s + chunk; if (e > E) e = E;
    for (int j = s + threadIdx.x; j < e; j += 256)
        atomicAdd(&lh[dst[j] >> BSH], 1);
    __syncthreads();
    for (int i = threadIdx.x; i < nbv; i += 256) {
        int c = lh[i];
        lbase[i] = c ? atomicAdd(&bcur[i], c) : 0;
        lh[i] = 0;                         // reuse as local cursor
    }
    __syncthreads();
    for (int j = s + threadIdx.x; j < e; j += 256) {
        int d = dst[j];
        int b = d >> BSH;
        int pos = atomicAdd(&lh[b], 1);
        tmp[lbase[b] + pos] = make_int2(src[j] | ((d & ((1 << BSH) - 1)) << 20),
                                        __float_as_int(ew[j]));
    }
}

// one block per bucket: in-LDS counting sort by local dst; emit CSR + row_start + dinv
__global__ __launch_bounds__(256)
void finalize_kernel(const int2* __restrict__ tmp, const int* __restrict__ bstart,
                     int2* __restrict__ se, int* __restrict__ row_start,
                     float* __restrict__ dinv, int n) {
    __shared__ int hist[128];
    __shared__ float degs[128];
    __shared__ int off[128];
    __shared__ int cur[128];
    __shared__ int2 stage[CAP];
    int b = blockIdx.x;
    int s0 = bstart[b], s1 = bstart[b + 1];
    int cnt = s1 - s0;
    int t = threadIdx.x;
    if (t < 128) { hist[t] = 0; degs[t] = 0.0f; cur[t] = 0; }
    __syncthreads();
    for (int j = s0 + t; j < s1; j += 256) {
        int2 r = tmp[j];
        int l = r.x >> 20;
        atomicAdd(&hist[l], 1);
        atomicAdd(&degs[l], __int_as_float(r.y));
    }
    __syncthreads();
    if (t < 128) off[t] = hist[t];
    __syncthreads();
    for (int o = 1; o < 128; o <<= 1) {           // inclusive scan
        int u = (t < 128 && t >= o) ? off[t - o] : 0;
        __syncthreads();
        if (t < 128) off[t] += u;
        __syncthreads();
    }
    if (t < 128) {
        int node = (b << BSH) + t;
        if (node < n) {
            row_start[node] = s0 + off[t] - hist[t];   // exclusive
            dinv[node] = rsqrtf(1.0f + degs[t]);
        }
    }
    __syncthreads();
    if (cnt <= CAP) {
        for (int j = s0 + t; j < s1; j += 256) {
            int2 r = tmp[j];
            int l = r.x >> 20;
            int p = (off[l] - hist[l]) + atomicAdd(&cur[l], 1);
            stage[p] = make_int2(r.x & 0xFFFFF, r.y);
        }
        __syncthreads();
        for (int k = t; k < cnt; k += 256) se[s0 + k] = stage[k];
    } else {   // overflow fallback (correctness net; not taken for this input)
        for (int j = s0 + t; j < s1; j += 256) {
            int2 r = tmp[j];
            int l = r.x >> 20;
            int p = (off[l] - hist[l]) + atomicAdd(&cur[l], 1);
            se[s0 + p] = make_int2(r.x & 0xFFFFF, r.y);
        }
    }
}

// hs[n,20](fp16) = ((in[n,FIN] @ W[FIN,20]) + cvec) * dinv[n]
template<int FIN, int NPB>
__global__ __launch_bounds__(256)
void gemm_kernel(const float* __restrict__ in, const float* __restrict__ W,
                 const float* __restrict__ cvec, const float* __restrict__ dinv,
                 __half* __restrict__ hs, int n) {
    __shared__ float sWt[HD][FIN + 4];
    __shared__ float sIn[NPB][FIN + 4];
    __shared__ float sC[HD];
    for (int i = threadIdx.x; i < FIN * HD; i += 256) {
        int k = i / HD, f = i % HD;           // W row-major [k][f]
        sWt[f][k] = W[i];
    }
    if (threadIdx.x < HD) sC[threadIdx.x] = cvec[threadIdx.x];
    int base = blockIdx.x * NPB;
    int nb = n - base; if (nb > NPB) nb = NPB;
    int lim = n * FIN;
    const int Q = FIN / 4;
    for (int i = threadIdx.x; i < NPB * Q; i += 256) {
        int row = i / Q, c = (i % Q) * 4;
        int g = (base + row) * FIN + c;
        *(float4*)&sIn[row][c] = (g < lim) ? *(const float4*)&in[g]
                                           : make_float4(0.f, 0.f, 0.f, 0.f);
    }
    __syncthreads();
    for (int idx = threadIdx.x; idx < NPB * HD; idx += 256) {
        int nl = idx / HD, f = idx % HD;
        float4 a = make_float4(0.f, 0.f, 0.f, 0.f);
        #pragma unroll 4
        for (int k = 0; k < FIN; k += 4) {
            float4 x4 = *(const float4*)&sIn[nl][k];
            float4 w4 = *(const float4*)&sWt[f][k];
            a.x = fmaf(x4.x, w4.x, a.x);
            a.y = fmaf(x4.y, w4.y, a.y);
            a.z = fmaf(x4.z, w4.z, a.z);
            a.w = fmaf(x4.w, w4.w, a.w);
        }
        if (nl < nb)
            hs[(base + nl) * HD + f] = __float2half_rn(
                (((a.x + a.y) + (a.z + a.w)) + sC[f]) * dinv[base + nl]);
    }
}

#define FMA4(A, V, W) \
    A.x = fmaf(V.x, W, A.x); A.y = fmaf(V.y, W, A.y); \
    A.z = fmaf(V.z, W, A.z); A.w = fmaf(V.w, W, A.w);

__device__ __forceinline__ float4 h4f2(uint2 u) {
    float2 f0 = __half22float2(*reinterpret_cast<const __half2*>(&u.x));
    float2 f1 = __half22float2(*reinterpret_cast<const __half2*>(&u.y));
    return make_float4(f0.x, f0.y, f1.x, f1.y);
}

// MODE 0: layers 1/2 — write o row + BN stats.
// MODE 1: layer 3 — fuse final linear: out[i,0..9] from o1,o2 rows + in-reg o3.
// One node per 4-lane group; 2-deep software-pipelined edge loop.
template<int MODE>
__global__ __launch_bounds__(256)
void agg_kernel(const uint2* __restrict__ hs4, const float* __restrict__ dinv,
                const int* __restrict__ row_start, const int2* __restrict__ se,
                const float* __restrict__ bias, float* __restrict__ out,
                float* __restrict__ stat_sum, float* __restrict__ stat_sq,
                const float* __restrict__ o1, const float* __restrict__ o2,
                const float* __restrict__ Wlp, const float* __restrict__ blp,
                int n) {
    __shared__ float ls[HD], lq[HD];
    __shared__ float sW[600];
    __shared__ float sb[10];
    if (MODE == 0) {
        if (threadIdx.x < HD) { ls[threadIdx.x] = 0.0f; lq[threadIdx.x] = 0.0f; }
        __syncthreads();
    } else {
        for (int i = threadIdx.x; i < 600; i += 256) sW[i] = Wlp[i];
        if (threadIdx.x < 10) sb[threadIdx.x] = blp[threadIdx.x];
        __syncthreads();
    }
    int t = blockIdx.x * blockDim.x + threadIdx.x;
    int i = t >> 2, lane = t & 3;
    if (i < n) {
        float di = dinv[i];
        int s0 = row_start[i], s1 = row_start[i + 1];
        float4 a0, a1, a2, a3, a4;
        if (lane == 0) {
            const uint2* s = hs4 + i * 5;
            a0 = h4f2(s[0]); a1 = h4f2(s[1]); a2 = h4f2(s[2]);
            a3 = h4f2(s[3]); a4 = h4f2(s[4]);
        } else {
            a0 = a1 = a2 = a3 = a4 = make_float4(0.f, 0.f, 0.f, 0.f);
        }
        int j = s0 + lane;
        if (j < s1) {
            // prologue: load first edge
            int2 e = se[j];
            float w = __int_as_float(e.y);
            const uint2* r = hs4 + e.x * 5;
            uint2 c0 = r[0], c1 = r[1], c2 = r[2], c3 = r[3], c4 = r[4];
            while (true) {
                int jn = j + 4;
                bool more = jn < s1;
                int jp = more ? jn : j;          // clamp: re-load warm row at end
                int2 en = se[jp];
                const uint2* rn = hs4 + en.x * 5;
                uint2 n0 = rn[0], n1 = rn[1], n2 = rn[2], n3 = rn[3], n4 = rn[4];
                float wn = __int_as_float(en.y);
                // consume current while next is in flight
                float4 v0 = h4f2(c0), v1 = h4f2(c1), v2 = h4f2(c2);
                float4 v3 = h4f2(c3), v4 = h4f2(c4);
                FMA4(a0, v0, w) FMA4(a1, v1, w) FMA4(a2, v2, w)
                FMA4(a3, v3, w) FMA4(a4, v4, w)
                if (!more) break;
                j = jn; w = wn;
                c0 = n0; c1 = n1; c2 = n2; c3 = n3; c4 = n4;
            }
        }
        #define REDX(A, M) \
            A.x += __shfl_xor(A.x, M); A.y += __shfl_xor(A.y, M); \
            A.z += __shfl_xor(A.z, M); A.w += __shfl_xor(A.w, M);
        #define RED4L(A) REDX(A, 1) REDX(A, 2)
        RED4L(a0) RED4L(a1) RED4L(a2) RED4L(a3) RED4L(a4)
        // all 4 lanes now hold the full sums
        float4 acc[5] = {a0, a1, a2, a3, a4};
        float va[HD];
        #pragma unroll
        for (int q = 0; q < 5; ++q) {
            float4 bb = *(const float4*)(bias + 4 * q);
            va[4 * q + 0] = fmaxf(fmaf(acc[q].x, di, bb.x), 0.0f);
            va[4 * q + 1] = fmaxf(fmaf(acc[q].y, di, bb.y), 0.0f);
            va[4 * q + 2] = fmaxf(fmaf(acc[q].z, di, bb.z), 0.0f);
            va[4 * q + 3] = fmaxf(fmaf(acc[q].w, di, bb.w), 0.0f);
        }
        if (MODE == 0) {
            if (lane == 0) {
                #pragma unroll
                for (int q = 0; q < 5; ++q) {
                    ((float4*)out)[i * 5 + q] = make_float4(
                        va[4 * q], va[4 * q + 1], va[4 * q + 2], va[4 * q + 3]);
                    int f = 4 * q;
                    atomicAdd(&ls[f + 0], va[f + 0]); atomicAdd(&lq[f + 0], va[f + 0] * va[f + 0]);
                    atomicAdd(&ls[f + 1], va[f + 1]); atomicAdd(&lq[f + 1], va[f + 1] * va[f + 1]);
                    atomicAdd(&ls[f + 2], va[f + 2]); atomicAdd(&lq[f + 2], va[f + 2] * va[f + 2]);
                    atomicAdd(&ls[f + 3], va[f + 3]); atomicAdd(&lq[f + 3], va[f + 3] * va[f + 3]);
                }
            }
        } else {
            // fused final: load o1,o2 rows (same addrs across quad -> L1 broadcast)
            float r1[HD], r2[HD];
            #pragma unroll
            for (int q = 0; q < 5; ++q) {
                *(float4*)&r1[4 * q] = ((const float4*)(o1 + (size_t)i * HD))[q];
                *(float4*)&r2[4 * q] = ((const float4*)(o2 + (size_t)i * HD))[q];
            }
            for (int c = lane; c < 10; c += 4) {
                float s = sb[c];
                #pragma unroll
                for (int k = 0; k < HD; ++k) s = fmaf(r1[k], sW[k * 10 + c], s);
                #pragma unroll
                for (int k = 0; k < HD; ++k) s = fmaf(r2[k], sW[(HD + k) * 10 + c], s);
                #pragma unroll
                for (int k = 0; k < HD; ++k) s = fmaf(va[k], sW[(2 * HD + k) * 10 + c], s);
                out[(size_t)i * 10 + c] = s;
            }
        }
    }
    if (MODE == 0) {
        __syncthreads();
        if (threadIdx.x < HD) {
            atomicAdd(&stat_sum[threadIdx.x], ls[threadIdx.x]);
            atomicAdd(&stat_sq[threadIdx.x], lq[threadIdx.x]);
        }
    }
}

// BN finalize + fold into next conv: scsh_out = (scale,shift);
// Wp[k][f] = sc[k]*W[k][f]; cvec[f] = sum_k sh[k]*W[k][f]
__global__ __launch_bounds__(512)
void bn_adjust_kernel(const float* __restrict__ sum, const float* __restrict__ sq,
                      const float* __restrict__ g, const float* __restrict__ be,
                      const float* __restrict__ W, float* __restrict__ scsh_out,
                      float* __restrict__ Wp, float* __restrict__ cvec, int n) {
    __shared__ float ssc[HD], ssh[HD];
    int t = threadIdx.x;
    if (t < HD) {
        float inv_n = 1.0f / (float)n;
        float m = sum[t] * inv_n;
        float var = sq[t] * inv_n - m * m;
        float sc = g[t] * rsqrtf(var + EPS);
        float sh = be[t] - m * sc;
        ssc[t] = sc; ssh[t] = sh;
        scsh_out[t] = sc; scsh_out[HD + t] = sh;
    }
    __syncthreads();
    if (t < HD * HD) Wp[t] = ssc[t / HD] * W[t];
    if (t < HD) {
        float acc = 0.0f;
        #pragma unroll
        for (int k = 0; k < HD; ++k) acc = fmaf(ssh[k], W[k * HD + t], acc);
        cvec[t] = acc;
    }
}

// second BN: same as above + build Wlp/blp for the fused final.
// Wlp rows: 0..19 *= sc1, 20..39 *= sc2, 40..59 UNSCALED (o3 block).
__global__ __launch_bounds__(640)
void bn_adjust2_kernel(const float* __restrict__ sum, const float* __restrict__ sq,
                       const float* __restrict__ g, const float* __restrict__ be,
                       const float* __restrict__ W, float* __restrict__ scsh_out,
                       float* __restrict__ Wp, float* __restrict__ cvec,
                       const float* __restrict__ Wl, const float* __restrict__ bl,
                       const float* __restrict__ scsh1,
                       float* __restrict__ Wlp, float* __restrict__ blp, int n) {
    __shared__ float ssc[HD], ssh[HD];
    int t = threadIdx.x;
    if (t < HD) {
        float inv_n = 1.0f / (float)n;
        float m = sum[t] * inv_n;
        float var = sq[t] * inv_n - m * m;
        float sc = g[t] * rsqrtf(var + EPS);
        float sh = be[t] - m * sc;
        ssc[t] = sc; ssh[t] = sh;
        scsh_out[t] = sc; scsh_out[HD + t] = sh;
    }
    __syncthreads();
    if (t < HD * HD) Wp[t] = ssc[t / HD] * W[t];
    if (t < HD) {
        float acc = 0.0f;
        #pragma unroll
        for (int k = 0; k < HD; ++k) acc = fmaf(ssh[k], W[k * HD + t], acc);
        cvec[t] = acc;
    }
    if (t < 600) {
        int k = t / 10;
        float s = (k < HD) ? scsh1[k] : (k < 2 * HD) ? ssc[k - HD] : 1.0f;  // FIX
        Wlp[t] = s * Wl[t];
    }
    if (t < 10) {
        float acc = bl[t];
        #pragma unroll
        for (int k = 0; k < HD; ++k) acc = fmaf(scsh1[HD + k], Wl[k * 10 + t], acc);
        #pragma unroll
        for (int k = 0; k < HD; ++k) acc = fmaf(ssh[k], Wl[(HD + k) * 10 + t], acc);
        blp[t] = acc;
    }
}

extern "C" void kernel_launch(void* const* d_in, const int* in_sizes, int n_in,
                              void* d_out, int out_size, void* d_ws, size_t ws_size,
                              hipStream_t stream) {
    const float* x   = (const float*)d_in[0];
    const int*   ei  = (const int*)d_in[1];
    const float* ew  = (const float*)d_in[2];
    const float* W1  = (const float*)d_in[3];
    const float* b1  = (const float*)d_in[4];
    const float* g1  = (const float*)d_in[5];
    const float* be1 = (const float*)d_in[6];
    const float* W2  = (const float*)d_in[7];
    const float* b2  = (const float*)d_in[8];
    const float* g2  = (const float*)d_in[9];
    const float* be2 = (const float*)d_in[10];
    const float* W3  = (const float*)d_in[11];
    const float* b3  = (const float*)d_in[12];
    const float* Wl  = (const float*)d_in[13];
    const float* bl  = (const float*)d_in[14];
    float* out = (float*)d_out;

    const int F = in_sizes[3] / HD;       // 128
    const int N = in_sizes[0] / F;        // 100000
    const int E = in_sizes[2];            // 3200000
    const int* src = ei;
    const int* dst = ei + E;
    const int nbv = (N + 127) >> BSH;     // 782 buckets

    char* p = (char*)d_ws;
    auto alloc = [&](size_t bytes) -> void* {
        void* r = (void*)p;
        p += (bytes + 255) & ~(size_t)255;
        return r;
    };
    size_t nh4 = (size_t)N * HD * 4;                         // 8e6 B
    int2*  se      = (int2*) alloc((size_t)E * 8);           // CSR payload (src, ew)
    char*  regionA = (char*) alloc((size_t)E * 8);           // tmp -> hs|_|o1r
    float* o2r     = (float*)alloc(nh4);
    float* dinv    = (float*)alloc((size_t)N * 4);
    int*   row_start = (int*)alloc((size_t)(N + 1) * 4);
    int*   bcnt    = (int*)  alloc(NBMAX * 4);
    int*   bstart  = (int*)  alloc((NBMAX + 1) * 4);
    int*   bcur    = (int*)  alloc(NBMAX * 4);
    float* stats   = (float*)alloc(80 * 4);   // sum1,sq1,sum2,sq2
    float* scsh    = (float*)alloc(80 * 4);   // sc1,sh1,sc2,sh2
    float* zero20  = (float*)alloc(20 * 4);
    float* W2p     = (float*)alloc(400 * 4);
    float* c2      = (float*)alloc(20 * 4);
    float* W3p     = (float*)alloc(400 * 4);
    float* c3      = (float*)alloc(20 * 4);
    float* Wlp     = (float*)alloc(600 * 4);
    float* blp     = (float*)alloc(12 * 4);

    int2*   tmp = (int2*)regionA;
    __half* hs  = (__half*)regionA;                 // 4 MB fp16, fits per-XCD L2
    float*  o1r = (float*)(regionA + 2 * nh4);

    const int B = 256;
    const int GB = 512;                          // blocks for hist/scatter
    const int chunk = (E + GB - 1) / GB;         // 6250
    int gAgg = (4 * N + B - 1) / B;              // 1563 (4 lanes/node)

    // ---- graph build (shared by all 3 layers) ----
    hipLaunchKernelGGL(init_kernel, dim3(1), dim3(1024), 0, stream, bcnt, stats, zero20, nbv);
    hipLaunchKernelGGL(bucket_hist_kernel, dim3(GB), dim3(B), 0, stream, dst, bcnt, E, chunk, nbv);
    hipLaunchKernelGGL(bucket_scan_kernel, dim3(1), dim3(1024), 0, stream,
                       bcnt, bstart, bcur, row_start, N, E, nbv);
    hipLaunchKernelGGL(scatter_kernel, dim3(GB), dim3(B), 0, stream,
                       src, dst, ew, bcur, tmp, E, chunk, nbv);
    hipLaunchKernelGGL(finalize_kernel, dim3(nbv), dim3(B), 0, stream,
                       tmp, bstart, se, row_start, dinv, N);

    // ---- layer 1 (no upstream BN: cvec = 0, bias = b1) ----
    hipLaunchKernelGGL((gemm_kernel<128, 16>), dim3((N + 15) / 16), dim3(B), 0, stream,
                       x, W1, zero20, dinv, hs, N);
    hipLaunchKernelGGL((agg_kernel<0>), dim3(gAgg), dim3(B), 0, stream,
                       (const uint2*)hs, dinv, row_start, se, b1, o1r,
                       stats, stats + 20, nullptr, nullptr, nullptr, nullptr, N);
    hipLaunchKernelGGL(bn_adjust_kernel, dim3(1), dim3(512), 0, stream,
                       stats, stats + 20, g1, be1, W2, scsh, W2p, c2, N);

    // ---- layer 2 (BN1 scale in W2p, shift in c2 pre-agg; bias = raw b2) ----
    hipLaunchKernelGGL((gemm_kernel<HD, 64>), dim3((N + 63) / 64), dim3(B), 0, stream,
                       o1r, W2p, c2, dinv, hs, N);
    hipLaunchKernelGGL((agg_kernel<0>), dim3(gAgg), dim3(B), 0, stream,
                       (const uint2*)hs, dinv, row_start, se, b2, o2r,
                       stats + 40, stats + 60, nullptr, nullptr, nullptr, nullptr, N);
    hipLaunchKernelGGL(bn_adjust2_kernel, dim3(1), dim3(640), 0, stream,
                       stats + 40, stats + 60, g2, be2, W3, scsh + 40, W3p, c3,
                       Wl, bl, scsh, Wlp, blp, N);

    // ---- layer 3 + fused final linear (writes d_out directly) ----
    hipLaunchKernelGGL((gemm_kernel<HD, 64>), dim3((N + 63) / 64), dim3(B), 0, stream,
                       o2r, W3p, c3, dinv, hs, N);
    hipLaunchKernelGGL((agg_kernel<1>), dim3(gAgg), dim3(B), 0, stream,
                       (const uint2*)hs, dinv, row_start, se, b3, out,
                       nullptr, nullptr, o1r, o2r, Wlp, blp, N);
}